// Round 1
// baseline (71.612 us; speedup 1.0000x reference)
//
#include <hip/hip_runtime.h>
#include <hip/hip_bf16.h>
#include <stdint.h>

// Problem constants: x [8,2048,768] f32, prototypes [1024,768] f32
// out = distances [16384,1024] f32  ++  prototypes copy [1024,768] f32
#define M_ROWS 16384
#define N_COLS 1024
#define K_DIM  768

typedef __attribute__((ext_vector_type(8))) short bf16x8;  // 8 bf16 = 4 VGPR
typedef __attribute__((ext_vector_type(4))) float f32x4;

__device__ __forceinline__ void async_copy16(void* lds, const void* g) {
  __builtin_amdgcn_global_load_lds(
      (const __attribute__((address_space(1))) unsigned int*)g,
      (__attribute__((address_space(3))) unsigned int*)lds,
      16, 0, 0);
}

// One block per row of K_DIM=768: f32->bf16 convert, fp32 sum-of-squares,
// optional fp32 passthrough copy (for the prototypes output).
__global__ void prep_rows(const float* __restrict__ src,
                          __hip_bfloat16* __restrict__ dstb,
                          float* __restrict__ sq,
                          float* __restrict__ copy_out) {
  const int row = blockIdx.x;
  const int tid = threadIdx.x;
  const float* r = src + (size_t)row * K_DIM;
  __hip_bfloat16* rb = dstb + (size_t)row * K_DIM;
  float acc = 0.f;
#pragma unroll
  for (int i = 0; i < 3; ++i) {
    int idx = tid + i * 256;
    float v = r[idx];
    acc += v * v;
    rb[idx] = __float2bfloat16(v);
    if (copy_out) copy_out[(size_t)row * K_DIM + idx] = v;
  }
  // wave reduce (64 lanes), then cross-wave via LDS
#pragma unroll
  for (int off = 32; off > 0; off >>= 1) acc += __shfl_down(acc, off, 64);
  __shared__ float red[4];
  if ((tid & 63) == 0) red[tid >> 6] = acc;
  __syncthreads();
  if (tid == 0) sq[row] = red[0] + red[1] + red[2] + red[3];
}

// 128x128 tile, BK=32, 256 threads = 4 waves (2x2), 64x64 per wave.
// A = x_bf16 [M,K] row-major; B = proto_bf16 [N,K] row-major (K contiguous,
// which is exactly the mfma_f32_16x16x32_bf16 B-fragment layout: lane l holds
// B[k=(l>>4)*8+j][col=l&15] -> read 8 contiguous k at row (l&15)).
__global__ void dist_gemm(const __hip_bfloat16* __restrict__ xb,
                          const __hip_bfloat16* __restrict__ pb,
                          const float* __restrict__ xsq,
                          const float* __restrict__ psq,
                          float* __restrict__ out) {
  __shared__ __hip_bfloat16 As[128 * 32];  // 8 KB, [row][32] row-major
  __shared__ __hip_bfloat16 Bs[128 * 32];  // 8 KB

  const int bm = blockIdx.y;
  const int bn = blockIdx.x;
  const int tid = threadIdx.x;
  const int wave = tid >> 6;
  const int lane = tid & 63;
  const int wm = wave >> 1;   // 0..1
  const int wn = wave & 1;    // 0..1

  f32x4 acc[4][4];
#pragma unroll
  for (int i = 0; i < 4; ++i)
#pragma unroll
    for (int j = 0; j < 4; ++j) {
      f32x4 z = {0.f, 0.f, 0.f, 0.f};
      acc[i][j] = z;
    }

  const __hip_bfloat16* Ab = xb + (size_t)(bm * 128) * K_DIM;
  const __hip_bfloat16* Bb = pb + (size_t)(bn * 128) * K_DIM;

  // staging: linear idx = c*256 + tid covers 512 chunks of 16B = 8KB tile
  // row = idx>>2 (4 threads x 16B = one 64B row of 32 bf16), col8 = (idx&3)*8
  const int r0 = tid >> 2;
  const int c8 = (tid & 3) * 8;  // bf16 element offset in row

  // LDS fragment read addressing (per lane)
  const int rA = lane & 15;          // fragment row/col
  const int kb = (lane >> 4) * 16;   // byte offset along K (8 bf16)

  for (int k0 = 0; k0 < K_DIM; k0 += 32) {
#pragma unroll
    for (int c = 0; c < 2; ++c) {
      const int row = c * 64 + r0;
      const int lofs = (c * 256 + tid) * 16;  // bytes, linear in thread order
      async_copy16((char*)As + lofs, Ab + (size_t)row * K_DIM + k0 + c8);
      async_copy16((char*)Bs + lofs, Bb + (size_t)row * K_DIM + k0 + c8);
    }
    __syncthreads();  // drains vmcnt (global_load_lds) + lgkm

    bf16x8 a[4], b[4];
#pragma unroll
    for (int i = 0; i < 4; ++i) {
      a[i] = *(const bf16x8*)((const char*)As + ((wm * 64 + i * 16 + rA) * 64 + kb));
      b[i] = *(const bf16x8*)((const char*)Bs + ((wn * 64 + i * 16 + rA) * 64 + kb));
    }
#pragma unroll
    for (int i = 0; i < 4; ++i)
#pragma unroll
      for (int j = 0; j < 4; ++j)
        acc[i][j] = __builtin_amdgcn_mfma_f32_16x16x32_bf16(a[i], b[j], acc[i][j], 0, 0, 0);
    __syncthreads();
  }

  // epilogue: dist = xsq[row] + psq[col] - 2*acc
  // C/D layout (m89-verified): col = lane&15, row = (lane>>4)*4 + reg
  const int colf = lane & 15;
  const int rowg = (lane >> 4) * 4;
#pragma unroll
  for (int j = 0; j < 4; ++j) {
    const int col = bn * 128 + wn * 64 + j * 16 + colf;
    const float ps = psq[col];
#pragma unroll
    for (int i = 0; i < 4; ++i) {
      const int rbase = bm * 128 + wm * 64 + i * 16 + rowg;
#pragma unroll
      for (int r = 0; r < 4; ++r) {
        const int row = rbase + r;
        out[(size_t)row * N_COLS + col] = xsq[row] + ps - 2.0f * acc[i][j][r];
      }
    }
  }
}

extern "C" void kernel_launch(void* const* d_in, const int* in_sizes, int n_in,
                              void* d_out, int out_size, void* d_ws, size_t ws_size,
                              hipStream_t stream) {
  const float* x = (const float*)d_in[0];      // 16384*768
  const float* p = (const float*)d_in[1];      // 1024*768
  float* out = (float*)d_out;                  // distances then proto copy
  char* ws = (char*)d_ws;

  // ws layout (all 16B-aligned): xsq | psq | x_bf16 | p_bf16  (~25.6 MB)
  float* xsq = (float*)ws;                                   // 64 KB
  float* psq = (float*)(ws + 65536);                         // 4 KB
  __hip_bfloat16* xb = (__hip_bfloat16*)(ws + 69632);        // 24 MB
  __hip_bfloat16* pb = (__hip_bfloat16*)(ws + 69632 + (size_t)M_ROWS * K_DIM * 2);
  float* proto_out = out + (size_t)M_ROWS * N_COLS;

  prep_rows<<<M_ROWS, 256, 0, stream>>>(x, xb, xsq, nullptr);
  prep_rows<<<N_COLS, 256, 0, stream>>>(p, pb, psq, proto_out);

  dim3 grid(N_COLS / 128, M_ROWS / 128);  // (8, 128)
  dist_gemm<<<grid, 256, 0, stream>>>(xb, pb, xsq, psq, out);
}

// Round 2
// 57.413 us; speedup vs baseline: 1.2473x; 1.2473x over previous
//
#include <hip/hip_runtime.h>
#include <hip/hip_bf16.h>
#include <stdint.h>

// x [8,2048,768] f32, prototypes [1024,768] f32
// out = distances [16384,1024] f32 ++ prototypes copy [1024,768] f32
#define M_ROWS 16384
#define N_COLS 1024
#define K_DIM  768

typedef __attribute__((ext_vector_type(8))) short bf16x8;
typedef __attribute__((ext_vector_type(4))) float f32x4;

__device__ __forceinline__ void async_copy16(void* lds, const void* g) {
  __builtin_amdgcn_global_load_lds(
      (const __attribute__((address_space(1))) unsigned int*)g,
      (__attribute__((address_space(3))) unsigned int*)lds,
      16, 0, 0);
}

__device__ __forceinline__ unsigned short f2bf(float f) {
  __hip_bfloat16 h = __float2bfloat16(f);
  return *reinterpret_cast<unsigned short*>(&h);
}

// wave-per-row: f32->bf16 convert (vectorized), fp32 ||row||^2, optional copy.
__global__ void prep_rows(const float* __restrict__ src,
                          unsigned short* __restrict__ dstb,
                          float* __restrict__ sq,
                          float* __restrict__ copy_out) {
  const int wid = threadIdx.x >> 6;
  const int lane = threadIdx.x & 63;
  const int row = blockIdx.x * 4 + wid;
  const float4* r = (const float4*)(src + (size_t)row * K_DIM);
  ushort4* rb = (ushort4*)(dstb + (size_t)row * K_DIM);
  float4* cp = copy_out ? (float4*)(copy_out + (size_t)row * K_DIM) : nullptr;
  float acc = 0.f;
#pragma unroll
  for (int i = 0; i < 3; ++i) {
    float4 v = r[i * 64 + lane];
    acc += v.x * v.x + v.y * v.y + v.z * v.z + v.w * v.w;
    ushort4 u;
    u.x = f2bf(v.x); u.y = f2bf(v.y); u.z = f2bf(v.z); u.w = f2bf(v.w);
    rb[i * 64 + lane] = u;
    if (cp) cp[i * 64 + lane] = v;
  }
#pragma unroll
  for (int off = 32; off; off >>= 1) acc += __shfl_down(acc, off);
  if (lane == 0) sq[row] = acc;
}

// 128x128 tile, BK=32, 4 waves (2x2), 64x64/wave, mfma_f32_16x16x32_bf16.
// LDS layout XOR-swizzled: byte(row, slot) = row*64 + (slot ^ ((row>>1)&3))*16
// (slot = 16B chunk along K). Swizzle applied on BOTH the pre-swizzled global
// source for global_load_lds (linear LDS dest) and the ds_read address.
__global__ void dist_gemm(const __hip_bfloat16* __restrict__ xb,
                          const __hip_bfloat16* __restrict__ pb,
                          const float* __restrict__ xsq,
                          const float* __restrict__ psq,
                          float* __restrict__ out) {
  __shared__ __hip_bfloat16 As[128 * 32];  // 8 KB
  __shared__ __hip_bfloat16 Bs[128 * 32];  // 8 KB

  // XCD-aware swizzle: grid=1024, 8 XCDs. XCD x owns bm in [x*16, x*16+16),
  // all 8 bn. Per-XCD L2 set: 16 A-panels (3MB bf16) + whole B (1.5MB).
  const int flat = blockIdx.x;
  const int xcd = flat & 7;
  const int local = flat >> 3;
  const int bm = xcd * 16 + (local >> 3);
  const int bn = local & 7;

  const int tid = threadIdx.x;
  const int wave = tid >> 6;
  const int lane = tid & 63;
  const int wm = wave >> 1;
  const int wn = wave & 1;

  f32x4 acc[4][4];
#pragma unroll
  for (int i = 0; i < 4; ++i)
#pragma unroll
    for (int j = 0; j < 4; ++j) {
      f32x4 z = {0.f, 0.f, 0.f, 0.f};
      acc[i][j] = z;
    }

  const __hip_bfloat16* Ab = xb + (size_t)(bm * 128) * K_DIM;
  const __hip_bfloat16* Bb = pb + (size_t)(bn * 128) * K_DIM;

  // staging: thread t, chunk c -> LDS linear bytes (c*256+t)*16.
  // That byte range is row = c*64 + t/4, stored-slot = t&3.
  // Pre-swizzle source: global slot g = (t&3) ^ ((row>>1)&3).
  const int sr[2] = {tid >> 2, 64 + (tid >> 2)};
  int gofs[2];
#pragma unroll
  for (int c = 0; c < 2; ++c) {
    const int row = sr[c];
    const int g = (tid & 3) ^ ((row >> 1) & 3);
    gofs[c] = row * K_DIM + g * 8;  // elements
  }

  // read-side: lane reads fragment row fr, k-slot ks=(lane>>4);
  // LDS byte = fr*64 + (ks ^ ((fr>>1)&3))*16
  const int rA = lane & 15;
  const int ks = lane >> 4;

  for (int k0 = 0; k0 < K_DIM; k0 += 32) {
#pragma unroll
    for (int c = 0; c < 2; ++c) {
      const int lofs = (c * 256 + tid) * 16;
      async_copy16((char*)As + lofs, Ab + gofs[c] + k0);
      async_copy16((char*)Bs + lofs, Bb + gofs[c] + k0);
    }
    __syncthreads();

    bf16x8 a[4], b[4];
#pragma unroll
    for (int i = 0; i < 4; ++i) {
      const int ra = wm * 64 + i * 16 + rA;
      const int rb = wn * 64 + i * 16 + rA;
      a[i] = *(const bf16x8*)((const char*)As + (ra * 64 + ((ks ^ ((ra >> 1) & 3)) * 16)));
      b[i] = *(const bf16x8*)((const char*)Bs + (rb * 64 + ((ks ^ ((rb >> 1) & 3)) * 16)));
    }
#pragma unroll
    for (int i = 0; i < 4; ++i)
#pragma unroll
      for (int j = 0; j < 4; ++j)
        acc[i][j] = __builtin_amdgcn_mfma_f32_16x16x32_bf16(a[i], b[j], acc[i][j], 0, 0, 0);
    __syncthreads();
  }

  // epilogue: dist = xsq[row] + psq[col] - 2*acc
  // C/D layout: col = lane&15, row = (lane>>4)*4 + reg
  const int colf = lane & 15;
  const int rowg = (lane >> 4) * 4;
#pragma unroll
  for (int j = 0; j < 4; ++j) {
    const int col = bn * 128 + wn * 64 + j * 16 + colf;
    const float ps = psq[col];
#pragma unroll
    for (int i = 0; i < 4; ++i) {
      const int rbase = bm * 128 + wm * 64 + i * 16 + rowg;
#pragma unroll
      for (int r = 0; r < 4; ++r) {
        const int row = rbase + r;
        out[(size_t)row * N_COLS + col] = xsq[row] + ps - 2.0f * acc[i][j][r];
      }
    }
  }
}

extern "C" void kernel_launch(void* const* d_in, const int* in_sizes, int n_in,
                              void* d_out, int out_size, void* d_ws, size_t ws_size,
                              hipStream_t stream) {
  const float* x = (const float*)d_in[0];
  const float* p = (const float*)d_in[1];
  float* out = (float*)d_out;
  char* ws = (char*)d_ws;

  float* xsq = (float*)ws;                                   // 64 KB
  float* psq = (float*)(ws + 65536);                         // 4 KB
  unsigned short* xb = (unsigned short*)(ws + 69632);        // 24 MB
  unsigned short* pb = xb + (size_t)M_ROWS * K_DIM;
  float* proto_out = out + (size_t)M_ROWS * N_COLS;

  prep_rows<<<M_ROWS / 4, 256, 0, stream>>>(x, xb, xsq, nullptr);
  prep_rows<<<N_COLS / 4, 256, 0, stream>>>(p, pb, psq, proto_out);

  dist_gemm<<<1024, 256, 0, stream>>>((const __hip_bfloat16*)xb,
                                      (const __hip_bfloat16*)pb,
                                      xsq, psq, out);
}

// Round 3
// 51.977 us; speedup vs baseline: 1.3778x; 1.1046x over previous
//
#include <hip/hip_runtime.h>
#include <hip/hip_bf16.h>
#include <stdint.h>

// x [8,2048,768] f32, prototypes [1024,768] f32
// out = distances [16384,1024] f32 ++ prototypes copy [1024,768] f32
#define M_ROWS 16384
#define N_COLS 1024
#define K_DIM  768
#define NKT    12   // K_DIM / 64

typedef __attribute__((ext_vector_type(8))) short bf16x8;
typedef __attribute__((ext_vector_type(4))) float f32x4;

__device__ __forceinline__ void async_copy16(void* lds, const void* g) {
  __builtin_amdgcn_global_load_lds(
      (const __attribute__((address_space(1))) unsigned int*)g,
      (__attribute__((address_space(3))) unsigned int*)lds,
      16, 0, 0);
}

__device__ __forceinline__ unsigned short f2bf(float f) {
  __hip_bfloat16 h = __float2bfloat16(f);
  return *reinterpret_cast<unsigned short*>(&h);
}

// wave-per-row: f32->bf16 convert (vectorized), fp32 ||row||^2, optional copy.
__global__ void prep_rows(const float* __restrict__ src,
                          unsigned short* __restrict__ dstb,
                          float* __restrict__ sq,
                          float* __restrict__ copy_out) {
  const int wid = threadIdx.x >> 6;
  const int lane = threadIdx.x & 63;
  const int row = blockIdx.x * 4 + wid;
  const float4* r = (const float4*)(src + (size_t)row * K_DIM);
  ushort4* rb = (ushort4*)(dstb + (size_t)row * K_DIM);
  float4* cp = copy_out ? (float4*)(copy_out + (size_t)row * K_DIM) : nullptr;
  float acc = 0.f;
#pragma unroll
  for (int i = 0; i < 3; ++i) {
    float4 v = r[i * 64 + lane];
    acc += v.x * v.x + v.y * v.y + v.z * v.z + v.w * v.w;
    ushort4 u;
    u.x = f2bf(v.x); u.y = f2bf(v.y); u.z = f2bf(v.z); u.w = f2bf(v.w);
    rb[i * 64 + lane] = u;
    if (cp) cp[i * 64 + lane] = v;
  }
#pragma unroll
  for (int off = 32; off; off >>= 1) acc += __shfl_down(acc, off);
  if (lane == 0) sq[row] = acc;
}

// LDS tile layout: [256 rows][64 bf16] = 128 B rows, 8 x 16B slots per row.
// Swizzle: stored slot = logical slot ^ (row & 7). Applied on pre-swizzled
// global source (linear global_load_lds dest) AND on ds_read address.
__device__ __forceinline__ bf16x8 ldsfrag(const char* tile, int row, int slot) {
  return *(const bf16x8*)(tile + row * 128 + (((slot ^ (row & 7)) << 4)));
}

// 256x256 tile, BK=64, 512 threads = 8 waves (2M x 4N), 128x64 out per wave.
// 4 phases per K-tile; stage one half-tile of kt+1 per phase; raw s_barrier;
// vmcnt(0) drain only at K-tile boundary (loads issued a full tile earlier).
__global__ __launch_bounds__(512, 2) void dist_gemm(
    const __hip_bfloat16* __restrict__ xb,
    const __hip_bfloat16* __restrict__ pb,
    const float* __restrict__ xsq,
    const float* __restrict__ psq,
    float* __restrict__ out) {
  __shared__ char lds[2][2][32768];  // [buf][A/B][256x64 bf16] = 128 KB

  // XCD swizzle: 256 blocks, xcd = flat&7 owns bm in [xcd*8, xcd*8+8), all bn.
  const int flat = blockIdx.x;
  const int xcd = flat & 7;
  const int local = flat >> 3;        // 0..31
  const int bm = xcd * 8 + (local >> 2);  // 0..63
  const int bn = local & 3;               // 0..3

  const int tid = threadIdx.x;
  const int wave = tid >> 6;
  const int lane = tid & 63;
  const int wm = wave >> 2;   // 0..1 (128 rows)
  const int wn = wave & 3;    // 0..3 (64 cols)
  const int rl = lane & 15;
  const int kq = lane >> 4;   // 0..3

  f32x4 acc[8][4] = {};
  bf16x8 af[4][2], bfr[4][2];

  const __hip_bfloat16* Abase = xb + (size_t)(bm * 256) * K_DIM;
  const __hip_bfloat16* Bbase = pb + (size_t)(bn * 256) * K_DIM;

  // staging: thread t stages 2 chunks per half-tile; chunk c ->
  // row-in-half = c*64 + (t>>3), stored slot = t&7, source slot pre-swizzled.
  const int rih = tid >> 3;                          // 0..63
  const int g8 = (((tid & 7) ^ (rih & 7))) * 8;      // source k-elem offset

#define STAGE(base, tile, h, ktile)                                          \
  do {                                                                       \
    _Pragma("unroll") for (int c = 0; c < 2; ++c) {                          \
      async_copy16((tile) + (h) * 16384 + (c * 512 + tid) * 16,              \
                   (base) + (size_t)((h) * 128 + c * 64 + rih) * K_DIM +     \
                       (ktile) * 64 + g8);                                   \
    }                                                                        \
  } while (0)

  // prologue: stage kt=0 fully into buf0
  {
    char* A0 = &lds[0][0][0];
    char* B0 = &lds[0][1][0];
    STAGE(Abase, A0, 0, 0);
    STAGE(Abase, A0, 1, 0);
    STAGE(Bbase, B0, 0, 0);
    STAGE(Bbase, B0, 1, 0);
  }
  asm volatile("s_waitcnt vmcnt(0)" ::: "memory");
  asm volatile("s_barrier" ::: "memory");

  for (int kt = 0; kt < NKT; ++kt) {
    const char* At = &lds[kt & 1][0][0];
    const char* Bt = &lds[kt & 1][1][0];
    char* An = &lds[(kt + 1) & 1][0][0];
    char* Bn = &lds[(kt + 1) & 1][1][0];
    const bool pf = (kt + 1 < NKT);

    // ---- phase 0: quadrant (mq=0, nq=0) ----
#pragma unroll
    for (int mi = 0; mi < 4; ++mi)
#pragma unroll
      for (int kk = 0; kk < 2; ++kk)
        af[mi][kk] = ldsfrag(At, wm * 128 + mi * 16 + rl, kk * 4 + kq);
#pragma unroll
    for (int ni = 0; ni < 2; ++ni)
#pragma unroll
      for (int kk = 0; kk < 2; ++kk)
        bfr[ni][kk] = ldsfrag(Bt, wn * 64 + ni * 16 + rl, kk * 4 + kq);
    if (pf) STAGE(Abase, An, 0, kt + 1);
    asm volatile("s_barrier" ::: "memory");
    __builtin_amdgcn_s_setprio(1);
#pragma unroll
    for (int mi = 0; mi < 4; ++mi)
#pragma unroll
      for (int ni = 0; ni < 2; ++ni)
#pragma unroll
        for (int kk = 0; kk < 2; ++kk)
          acc[mi][ni] = __builtin_amdgcn_mfma_f32_16x16x32_bf16(
              af[mi][kk], bfr[ni][kk], acc[mi][ni], 0, 0, 0);
    __builtin_amdgcn_s_setprio(0);
    asm volatile("s_barrier" ::: "memory");

    // ---- phase 1: quadrant (mq=0, nq=1) ----
#pragma unroll
    for (int ni = 2; ni < 4; ++ni)
#pragma unroll
      for (int kk = 0; kk < 2; ++kk)
        bfr[ni][kk] = ldsfrag(Bt, wn * 64 + ni * 16 + rl, kk * 4 + kq);
    if (pf) STAGE(Abase, An, 1, kt + 1);
    asm volatile("s_barrier" ::: "memory");
    __builtin_amdgcn_s_setprio(1);
#pragma unroll
    for (int mi = 0; mi < 4; ++mi)
#pragma unroll
      for (int ni = 0; ni < 2; ++ni)
#pragma unroll
        for (int kk = 0; kk < 2; ++kk)
          acc[mi][2 + ni] = __builtin_amdgcn_mfma_f32_16x16x32_bf16(
              af[mi][kk], bfr[2 + ni][kk], acc[mi][2 + ni], 0, 0, 0);
    __builtin_amdgcn_s_setprio(0);
    asm volatile("s_barrier" ::: "memory");

    // ---- phase 2: quadrant (mq=1, nq=0) ----
#pragma unroll
    for (int mi = 0; mi < 4; ++mi)
#pragma unroll
      for (int kk = 0; kk < 2; ++kk)
        af[mi][kk] = ldsfrag(At, wm * 128 + 64 + mi * 16 + rl, kk * 4 + kq);
    if (pf) STAGE(Bbase, Bn, 0, kt + 1);
    asm volatile("s_barrier" ::: "memory");
    __builtin_amdgcn_s_setprio(1);
#pragma unroll
    for (int mi = 0; mi < 4; ++mi)
#pragma unroll
      for (int ni = 0; ni < 2; ++ni)
#pragma unroll
        for (int kk = 0; kk < 2; ++kk)
          acc[4 + mi][ni] = __builtin_amdgcn_mfma_f32_16x16x32_bf16(
              af[mi][kk], bfr[ni][kk], acc[4 + mi][ni], 0, 0, 0);
    __builtin_amdgcn_s_setprio(0);
    asm volatile("s_barrier" ::: "memory");

    // ---- phase 3: quadrant (mq=1, nq=1) ----
    if (pf) STAGE(Bbase, Bn, 1, kt + 1);
    asm volatile("s_barrier" ::: "memory");
    __builtin_amdgcn_s_setprio(1);
#pragma unroll
    for (int mi = 0; mi < 4; ++mi)
#pragma unroll
      for (int ni = 0; ni < 2; ++ni)
#pragma unroll
        for (int kk = 0; kk < 2; ++kk)
          acc[4 + mi][2 + ni] = __builtin_amdgcn_mfma_f32_16x16x32_bf16(
              af[mi][kk], bfr[2 + ni][kk], acc[4 + mi][2 + ni], 0, 0, 0);
    __builtin_amdgcn_s_setprio(0);
    // K-tile boundary: drain kt+1's staging loads (issued >= 1 phase ago),
    // then barrier so every wave sees buf[(kt+1)&1] complete.
    asm volatile("s_waitcnt vmcnt(0)" ::: "memory");
    asm volatile("s_barrier" ::: "memory");
  }
#undef STAGE

  // epilogue: dist = xsq[row] + psq[col] - 2*acc
  // C/D layout: col = lane&15, row = (lane>>4)*4 + reg
  const int r0 = bm * 256 + wm * 128;
  const int c0 = bn * 256 + wn * 64;
#pragma unroll
  for (int mf = 0; mf < 8; ++mf) {
#pragma unroll
    for (int nf = 0; nf < 4; ++nf) {
      const int col = c0 + nf * 16 + rl;
      const float ps = psq[col];
#pragma unroll
      for (int r = 0; r < 4; ++r) {
        const int row = r0 + mf * 16 + kq * 4 + r;
        out[(size_t)row * N_COLS + col] = xsq[row] + ps - 2.0f * acc[mf][nf][r];
      }
    }
  }
}

extern "C" void kernel_launch(void* const* d_in, const int* in_sizes, int n_in,
                              void* d_out, int out_size, void* d_ws, size_t ws_size,
                              hipStream_t stream) {
  const float* x = (const float*)d_in[0];
  const float* p = (const float*)d_in[1];
  float* out = (float*)d_out;
  char* ws = (char*)d_ws;

  float* xsq = (float*)ws;                                   // 64 KB
  float* psq = (float*)(ws + 65536);                         // 4 KB
  unsigned short* xb = (unsigned short*)(ws + 69632);        // 24 MB
  unsigned short* pb = xb + (size_t)M_ROWS * K_DIM;
  float* proto_out = out + (size_t)M_ROWS * N_COLS;

  prep_rows<<<M_ROWS / 4, 256, 0, stream>>>(x, xb, xsq, nullptr);
  prep_rows<<<N_COLS / 4, 256, 0, stream>>>(p, pb, psq, proto_out);

  dist_gemm<<<256, 512, 0, stream>>>((const __hip_bfloat16*)xb,
                                     (const __hip_bfloat16*)pb,
                                     xsq, psq, out);
}